// Round 1
// baseline (11.379 us; speedup 1.0000x reference)
//
#include <hip/hip_runtime.h>
#include <math.h>

#define SQRT_2PI 2.5066282746310002f
#define N_ITERS 100

__global__ __launch_bounds__(128) void linearnet_fused(
    const float* __restrict__ x,    // (1,3)
    const float* __restrict__ u0,   // (1,1)
    const float* __restrict__ repa, // (100,1,1)
    const float* __restrict__ W_e1, // (50,4)
    const float* __restrict__ b_e1, // (50)
    const float* __restrict__ W_e2, // (2,50)
    const float* __restrict__ b_e2, // (2)
    const float* __restrict__ W_x1, // (10,1)
    const float* __restrict__ b_x1, // (10)
    const float* __restrict__ W_x2, // (2,10)
    const float* __restrict__ b_x2, // (2)
    const float* __restrict__ W_n1, // (10,1)
    const float* __restrict__ b_n1, // (10)
    const float* __restrict__ W_n2, // (1,10)
    const float* __restrict__ b_n2, // (1)
    float* __restrict__ out)        // [loss, z[0..99]]
{
    __shared__ float s_h[50];
    __shared__ float s_mean, s_var;
    __shared__ float s_red[128];

    const int tid = threadIdx.x;

    // ---- Phase 1: encoder 4 -> 50 (relu), lanes 0..49 ----
    const float e_in0 = u0[0];
    const float e_in1 = x[0];
    const float e_in2 = x[1];
    const float e_in3 = x[2];

    if (tid < 50) {
        float acc = b_e1[tid];
        acc += e_in0 * W_e1[tid * 4 + 0];
        acc += e_in1 * W_e1[tid * 4 + 1];
        acc += e_in2 * W_e1[tid * 4 + 2];
        acc += e_in3 * W_e1[tid * 4 + 3];
        s_h[tid] = fmaxf(acc, 0.0f);
    }
    __syncthreads();

    // ---- 50 -> 2 projection (thread 0; trivial) ----
    if (tid == 0) {
        float e0 = b_e2[0], e1 = b_e2[1];
        #pragma unroll
        for (int j = 0; j < 50; ++j) {
            const float hj = s_h[j];
            e0 += hj * W_e2[j];
            e1 += hj * W_e2[50 + j];
        }
        s_mean = e0;
        s_var  = e1;
    }
    __syncthreads();

    const float mean = s_mean;
    const float var  = s_var;

    // ud = PARAMS1[int(u0)-1, 0]; PARAMS1 = {-1, -4}
    const int   n  = (int)u0[0] - 1;
    const float ud = (n == 0) ? -1.0f : -4.0f;
    const float sigma  = sqrtf(-1.0f / (2.0f * ud));
    const float normal = 1.0f / (sigma * SQRT_2PI);

    // ---- Phase 2: 100 independent iterations ----
    float local = 0.0f;
    if (tid < N_ITERS) {
        const float r = repa[tid];
        const float z = mean + r * var;
        out[1 + tid] = z;  // z output, flat (100,1,1)

        // l2a = (z @ W_x1.T + b_x1) @ W_x2.T + b_x2   (1->10->2, no relu)
        float a0 = b_x2[0], a1 = b_x2[1];
        #pragma unroll
        for (int j = 0; j < 10; ++j) {
            const float hj = z * W_x1[j] + b_x1[j];
            a0 += hj * W_x2[j];
            a1 += hj * W_x2[10 + j];
        }
        // nonli = relu(z @ W_n1.T + b_n1) @ W_n2.T + b_n2  (1->10->1)
        float nl = b_n2[0];
        #pragma unroll
        for (int j = 0; j < 10; ++j) {
            const float hj = fmaxf(z * W_n1[j] + b_n1[j], 0.0f);
            nl += hj * W_n2[j];
        }

        const float d0 = a0 - e_in1;
        const float d1 = a1 - e_in2;
        const float d2 = nl - e_in3;
        const float nrm = sqrtf(d0 * d0 + d1 * d1 + d2 * d2);

        // l1 = exp(z^2 * ud) / normal ; loss2 = -log(l1) + 200*norm
        const float l1 = expf(z * z * ud) / normal;
        const float loss2 = -logf(l1) + nrm * 200.0f;

        // loss1 = exp(-r^2/2) / (sqrt(2pi) * |var|)
        const float loss1 = expf(-r * r * 0.5f) / (SQRT_2PI * fabsf(var));

        local = loss2 + logf(loss1);
    }

    // ---- Block reduction for loss ----
    s_red[tid] = local;
    __syncthreads();
    if (tid == 0) {
        float s = 0.0f;
        #pragma unroll
        for (int i = 0; i < N_ITERS; ++i) s += s_red[i];
        out[0] = s / (float)N_ITERS;
    }
}

extern "C" void kernel_launch(void* const* d_in, const int* in_sizes, int n_in,
                              void* d_out, int out_size, void* d_ws, size_t ws_size,
                              hipStream_t stream) {
    const float* x    = (const float*)d_in[0];
    const float* u0   = (const float*)d_in[1];
    const float* repa = (const float*)d_in[2];
    const float* W_e1 = (const float*)d_in[3];
    const float* b_e1 = (const float*)d_in[4];
    const float* W_e2 = (const float*)d_in[5];
    const float* b_e2 = (const float*)d_in[6];
    const float* W_x1 = (const float*)d_in[7];
    const float* b_x1 = (const float*)d_in[8];
    const float* W_x2 = (const float*)d_in[9];
    const float* b_x2 = (const float*)d_in[10];
    const float* W_n1 = (const float*)d_in[11];
    const float* b_n1 = (const float*)d_in[12];
    const float* W_n2 = (const float*)d_in[13];
    const float* b_n2 = (const float*)d_in[14];
    float* out = (float*)d_out;

    linearnet_fused<<<1, 128, 0, stream>>>(
        x, u0, repa,
        W_e1, b_e1, W_e2, b_e2,
        W_x1, b_x1, W_x2, b_x2,
        W_n1, b_n1, W_n2, b_n2,
        out);
}

// Round 2
// 9.368 us; speedup vs baseline: 1.2146x; 1.2146x over previous
//
#include <hip/hip_runtime.h>
#include <math.h>

#define SQRT_2PI 2.5066282746310002f
#define N_ITERS 100

__global__ __launch_bounds__(64) void linearnet_fused(
    const float* __restrict__ x,    // (1,3)
    const float* __restrict__ u0,   // (1,1)
    const float* __restrict__ repa, // (100,1,1)
    const float* __restrict__ W_e1, // (50,4)
    const float* __restrict__ b_e1, // (50)
    const float* __restrict__ W_e2, // (2,50)
    const float* __restrict__ b_e2, // (2)
    const float* __restrict__ W_x1, // (10,1)
    const float* __restrict__ b_x1, // (10)
    const float* __restrict__ W_x2, // (2,10)
    const float* __restrict__ b_x2, // (2)
    const float* __restrict__ W_n1, // (10,1)
    const float* __restrict__ b_n1, // (10)
    const float* __restrict__ W_n2, // (1,10)
    const float* __restrict__ b_n2, // (1)
    float* __restrict__ out)        // [loss, z[0..99]]
{
    const int lane = threadIdx.x;  // single wave of 64

    // ---- uniform scalar inputs (compiler scalarizes these) ----
    const float u00 = u0[0];
    const float x0 = x[0], x1 = x[1], x2 = x[2];

    // ---- per-lane repa values (lane and lane+64) ----
    const float r_a = repa[lane];
    const float r_b = (lane < N_ITERS - 64) ? repa[lane + 64] : 0.0f;

    // ---- Phase 1: encoder 4->50 relu, lanes 0..49 ----
    float h = 0.0f, we2a = 0.0f, we2b = 0.0f;
    if (lane < 50) {
        const float4 w = *reinterpret_cast<const float4*>(W_e1 + lane * 4);
        h = fmaxf(b_e1[lane] + u00 * w.x + x0 * w.y + x1 * w.z + x2 * w.w, 0.0f);
        we2a = W_e2[lane];
        we2b = W_e2[50 + lane];
    }

    // ---- 50 -> 2 projection via butterfly reduce (all lanes end with sums) ----
    float p0 = h * we2a;
    float p1 = h * we2b;
    #pragma unroll
    for (int m = 32; m >= 1; m >>= 1) {
        p0 += __shfl_xor(p0, m, 64);
        p1 += __shfl_xor(p1, m, 64);
    }
    const float mean = p0 + b_e2[0];
    const float var  = p1 + b_e2[1];

    // ud = PARAMS1[int(u0)-1, 0]; PARAMS1 = {-1, -4}
    const int   n  = (int)u00 - 1;
    const float ud = (n == 0) ? -1.0f : -4.0f;
    const float sigma = sqrtf(-1.0f / (2.0f * ud));

    // ---- Phase 2: per-iteration body (transcendentals algebraically removed):
    //   -log(l1)  = -z^2*ud + log(sigma*SQRT_2PI)           [uniform part hoisted]
    //   log(loss1)= -r^2/2  - log(SQRT_2PI*|var|)           [uniform part hoisted]
    //   per-lane contribution: -z^2*ud + 200*nrm - r^2/2
    const float bx20 = b_x2[0], bx21 = b_x2[1], bn20 = b_n2[0];

    auto iter_body = [&](float r, float& z_out) -> float {
        const float z = mean + r * var;
        z_out = z;
        float a0 = bx20, a1 = bx21, nl = bn20;
        #pragma unroll
        for (int j = 0; j < 10; ++j) {
            const float hj = z * W_x1[j] + b_x1[j];
            a0 += hj * W_x2[j];
            a1 += hj * W_x2[10 + j];
        }
        #pragma unroll
        for (int j = 0; j < 10; ++j) {
            const float hj = fmaxf(z * W_n1[j] + b_n1[j], 0.0f);
            nl += hj * W_n2[j];
        }
        const float d0 = a0 - x0;
        const float d1 = a1 - x1;
        const float d2 = nl - x2;
        const float nrm = sqrtf(d0 * d0 + d1 * d1 + d2 * d2);
        return -z * z * ud + 200.0f * nrm - 0.5f * r * r;
    };

    float za, zb;
    float local = iter_body(r_a, za);
    out[1 + lane] = za;
    if (lane < N_ITERS - 64) {
        local += iter_body(r_b, zb);
        out[1 + lane + 64] = zb;
    }

    // ---- loss butterfly reduce across the wave ----
    #pragma unroll
    for (int m = 32; m >= 1; m >>= 1) {
        local += __shfl_xor(local, m, 64);
    }

    if (lane == 0) {
        const float loss = local / (float)N_ITERS
                         - logf(sigma * SQRT_2PI)          // +log(normal)
                         - logf(SQRT_2PI * fabsf(var));    // +log(loss1) uniform part
        out[0] = loss;
    }
}

extern "C" void kernel_launch(void* const* d_in, const int* in_sizes, int n_in,
                              void* d_out, int out_size, void* d_ws, size_t ws_size,
                              hipStream_t stream) {
    const float* x    = (const float*)d_in[0];
    const float* u0   = (const float*)d_in[1];
    const float* repa = (const float*)d_in[2];
    const float* W_e1 = (const float*)d_in[3];
    const float* b_e1 = (const float*)d_in[4];
    const float* W_e2 = (const float*)d_in[5];
    const float* b_e2 = (const float*)d_in[6];
    const float* W_x1 = (const float*)d_in[7];
    const float* b_x1 = (const float*)d_in[8];
    const float* W_x2 = (const float*)d_in[9];
    const float* b_x2 = (const float*)d_in[10];
    const float* W_n1 = (const float*)d_in[11];
    const float* b_n1 = (const float*)d_in[12];
    const float* W_n2 = (const float*)d_in[13];
    const float* b_n2 = (const float*)d_in[14];
    float* out = (float*)d_out;

    linearnet_fused<<<1, 64, 0, stream>>>(
        x, u0, repa,
        W_e1, b_e1, W_e2, b_e2,
        W_x1, b_x1, W_x2, b_x2,
        W_n1, b_n1, W_n2, b_n2,
        out);
}